// Round 5
// baseline (586.853 us; speedup 1.0000x reference)
//
#include <hip/hip_runtime.h>
#include <stdint.h>

#define AS1 __attribute__((address_space(1)))
#define AS3 __attribute__((address_space(3)))

typedef short v8s  __attribute__((ext_vector_type(8)));
typedef float v4f  __attribute__((ext_vector_type(4)));
typedef float v16f __attribute__((ext_vector_type(16)));

#define C_IN  512
#define C_OUT 512
#define HW    64
#define COEF  9.20711955e-04f   // 1 / (16 * sqrt(9*512))

// E layout (R2 image): [pu(2)][ocb(16)][icb(16)] chunks of [tap(18)][oc_l(32)][slot(4)][16B]
#define E_CHUNK_SHORTS 18432
#define E_WS_BYTES     (2u*16u*16u*36864u)            // 18,874,368
// x_tp: [n(8)][hp(66)][wp(66)][512 ic] bf16, zero-padded border, ic-slot swizzled
#define XT_SHORTS      ((size_t)8*66*66*512)
#define XT_BYTES       (XT_SHORTS*2)                  // 35,684,352
#define WS_NEED        ((size_t)E_WS_BYTES + XT_BYTES)

// LDS: x tile [18 rows][34 cols][64B] = 39168 B, then E tile [18][32][64B] = 36864 B
#define XTILE_BYTES 39168
#define LDS_E_OFF   39168
#define LDS_BYTES   76032

__device__ __forceinline__ float Gf(int i) {
    return (i < 0 || i > 3) ? 0.f : ((i == 1 || i == 2) ? 3.f : 1.f);
}
__device__ __forceinline__ short f2bf(float f) {
    uint32_t u = __float_as_uint(f);
    u += 0x7fffu + ((u >> 16) & 1u);
    return (short)(u >> 16);
}

// ---------------- precompute: x -> padded NHWC bf16 via LDS transpose ----------
__global__ __launch_bounds__(256) void xpose_kernel(const float* __restrict__ x,
                                                    short* __restrict__ xt) {
    const int b     = blockIdx.x;
    const int icb64 = b & 7;
    const int hp    = (b >> 3) % 66;
    const int n     = (b >> 3) / 66;
    const int t     = threadIdx.x;

    __shared__ short tile[64][80];   // [w][ic_local]

    const bool hvalid = (hp >= 1 && hp <= 64);
    if (hvalid) {
        #pragma unroll
        for (int r = 0; r < 4; ++r) {
            const int i  = (t >> 4) + r * 16;     // ic_local 0..63
            const int w0 = (t & 15) * 4;          // w 0..63
            const float* src = x + ((size_t)(n * C_IN + icb64 * 64 + i) * HW + (hp - 1)) * HW + w0;
            float4 v = *(const float4*)src;
            tile[w0 + 0][i] = f2bf(v.x);
            tile[w0 + 1][i] = f2bf(v.y);
            tile[w0 + 2][i] = f2bf(v.z);
            tile[w0 + 3][i] = f2bf(v.w);
        }
    }
    __syncthreads();

    for (int u = t; u < 528; u += 256) {
        const int wp = u >> 3;
        const int gs = u & 7;
        v8s o = (v8s)0;
        if (hvalid && wp >= 1 && wp <= 64) {
            const int glog = (gs & 3) ^ ((wp >> 1) & 3);
            const int il   = (gs >> 2) * 32 + glog * 8;
            o = *(const v8s*)&tile[wp - 1][il];
        }
        *(v8s*)(xt + ((size_t)(n * 66 + hp) * 66 + wp) * 512
                   + icb64 * 64 + (gs >> 2) * 32 + (gs & 3) * 8) = o;
    }
}

// ---------------- precompute: E in block-LDS image layout, bf16, swizzled -------
__global__ __launch_bounds__(256) void prep_e_kernel(const float* __restrict__ w,
                                                     short* __restrict__ ews) {
    int u = blockIdx.x * 256 + threadIdx.x;   // 1,179,648 units of 16B
    int g    = u & 3;
    int oc_l = (u >> 2) & 31;
    int tq   = u >> 7;
    int tap  = tq % 18;
    int rest = tq / 18;                        // pu*256 + ocb*16 + icb
    int icb  = rest & 15;
    int ocb  = (rest >> 4) & 15;
    int pu   = rest >> 8;
    int pv   = tap & 1;
    int ts   = tap >> 1;
    int t    = ts / 3, s = ts - t * 3;
    int m    = 2 * t + 1 - pu;
    int nn   = 2 * s + 1 - pv;
    int glog = g ^ ((oc_l >> 1) & 3);
    int ic0  = icb * 32 + glog * 8;
    int oc   = ocb * 32 + oc_l;

    v8s o;
    #pragma unroll
    for (int j = 0; j < 8; ++j) {
        float acc = 0.f;
        #pragma unroll
        for (int p = 0; p < 3; ++p) {
            float gm = Gf(m - p);
            if (gm != 0.f) {
                #pragma unroll
                for (int q = 0; q < 3; ++q) {
                    float gn = Gf(nn - q);
                    if (gn != 0.f)
                        acc += gm * gn * w[((size_t)(p * 3 + q) * C_IN + ic0 + j) * C_OUT + oc];
                }
            }
        }
        o[j] = f2bf(acc * COEF);
    }
    *(v8s*)(ews + (size_t)u * 8) = o;
}

// ---------------- main MFMA kernel (32x32x16) -----------------------------------
__global__ __launch_bounds__(256, 2) void conv_mfma_kernel(const short* __restrict__ xt,
                                                           const short* __restrict__ ews,
                                                           float* __restrict__ out) {
    int bid  = blockIdx.x;
    int wgid = (bid & 7) * 256 + (bid >> 3);   // bijective XCD swizzle (2048 % 8 == 0)
    int vhb = wgid & 1;  wgid >>= 1;
    int uhb = wgid & 3;  wgid >>= 2;
    int n   = wgid & 7;  wgid >>= 3;
    int ocb = wgid & 15; wgid >>= 4;
    int pu  = wgid;
    const int uh0 = uhb * 16, vh0 = vhb * 32;

    __shared__ char lds_raw[LDS_BYTES];
    AS3 char* lds3 = (AS3 char*)lds_raw;

    const int tid  = threadIdx.x;
    const int lane = tid & 63;
    const int wid  = tid >> 6;      // wave's uh-quarter (0..3)
    const int l31  = lane & 31;
    const int hi   = lane >> 5;

    // x staging: 2448 units of 16B -> (row 0..17, col 0..33, slot 0..3)
    const short* gx[10];
    bool xact[10];
    #pragma unroll
    for (int it = 0; it < 10; ++it) {
        int unit  = it * 256 + tid;
        xact[it]  = unit < 2448;
        int chunk = unit >> 2;
        int cslot = unit & 3;
        int row   = chunk / 34;
        int c     = chunk - row * 34;
        if (!xact[it]) { row = 0; c = 0; }
        gx[it] = xt + ((size_t)(n * 66 + (uh0 + row)) * 66 + (vh0 + c)) * 512 + cslot * 8;
    }
    // E staging source (36864 B per icb: 9 iters x 256 lanes x 16B)
    const short* esrc0 = ews + ((size_t)((pu * 16 + ocb) * 16)) * E_CHUNK_SHORTS + (size_t)tid * 8;

    v16f acc[4][2];   // [u][pv]
    #pragma unroll
    for (int u = 0; u < 4; ++u)
        #pragma unroll
        for (int pv = 0; pv < 2; ++pv)
            acc[u][pv] = (v16f)0.f;

    const int ocx = (l31 >> 1) & 3;

    for (int icb = 0; icb < 16; ++icb) {
        __syncthreads();   // all waves done reading previous tiles
        // stage E (linear copy of pre-swizzled image)
        const short* es = esrc0 + (size_t)icb * E_CHUNK_SHORTS;
        #pragma unroll
        for (int it = 0; it < 9; ++it) {
            __builtin_amdgcn_global_load_lds((const AS1 void*)(es + it * 2048),
                (AS3 void*)(lds3 + LDS_E_OFF + (it * 256 + wid * 64) * 16), 16, 0, 0);
        }
        // stage x (pre-swizzled source, linear dest)
        #pragma unroll
        for (int it = 0; it < 10; ++it) {
            if (xact[it])
                __builtin_amdgcn_global_load_lds((const AS1 void*)(gx[it] + icb * 32),
                    (AS3 void*)(lds3 + (it * 256 + wid * 64) * 16), 16, 0, 0);
        }
        __syncthreads();   // compiler emits vmcnt(0) drain before this

        // compute: per s-shift, per 16-ic ksub: 6 A-frags (shared across 3 t), 6 B-frags
        #pragma unroll
        for (int s = 0; s < 3; ++s) {
            const int c  = l31 + s;            // tile col (vh + s)
            const int cx = (c >> 1) & 3;
            #pragma unroll
            for (int ksub = 0; ksub < 2; ++ksub) {
                const int slot = ksub * 2 + hi;            // 8-ic group within icb
                const char* xb = lds_raw + c * 64 + ((slot ^ cx) * 16);
                v8s A[6];
                #pragma unroll
                for (int rr = 0; rr < 6; ++rr)
                    A[rr] = *(const v8s*)(xb + (wid * 4 + rr) * (34 * 64));
                const int eoff = l31 * 64 + ((slot ^ ocx) * 16);
                #pragma unroll
                for (int t = 0; t < 3; ++t) {
                    #pragma unroll
                    for (int pv = 0; pv < 2; ++pv) {
                        v8s B = *(const v8s*)(lds_raw + LDS_E_OFF
                                              + ((t * 3 + s) * 2 + pv) * 2048 + eoff);
                        #pragma unroll
                        for (int u = 0; u < 4; ++u)
                            acc[u][pv] = __builtin_amdgcn_mfma_f32_32x32x16_bf16(
                                             A[u + t], B, acc[u][pv], 0, 0, 0);
                    }
                }
            }
        }
    }

    // epilogue: D col = lane&31 (oc), row = (reg&3) + 8*(reg>>2) + 4*(lane>>5) (vh)
    const int oc_g = ocb * 32 + l31;
    float* ob = out + ((size_t)(n * C_OUT + oc_g)) * 128 * 128;
    #pragma unroll
    for (int u = 0; u < 4; ++u) {
        const int h = 2 * (uh0 + wid * 4 + u) + pu;
        #pragma unroll
        for (int rg = 0; rg < 8; ++rg) {
            const int reg  = rg * 2;
            const int vh_l = (reg & 3) + 8 * (reg >> 2) + 4 * hi;
            v4f f;
            f[0] = acc[u][0][reg];
            f[1] = acc[u][1][reg];
            f[2] = acc[u][0][reg + 1];
            f[3] = acc[u][1][reg + 1];
            *(v4f*)(ob + (size_t)h * 128 + 2 * (vh0 + vh_l)) = f;
        }
    }
}

// ---------------- fallback (validated round-1 VALU kernel) ----------------------
#define ICB 8
#define UB  4
__global__ __launch_bounds__(256) void conv_par_kernel(
        const float* __restrict__ x, const float* __restrict__ w,
        float* __restrict__ out) {
    const int octile = blockIdx.x;
    const int n      = blockIdx.y >> 4;
    const int uhb    = blockIdx.y & 15;
    const int pu     = blockIdx.z >> 1;
    const int pv     = blockIdx.z & 1;
    const int t    = threadIdx.x;
    const int lane = t & 63;
    const int wg   = t >> 6;
    const int ocb  = octile * 64;
    const int uh0  = uhb * UB;
    __shared__ float xs[ICB][6][66];
    __shared__ float esw[9][ICB][64];
    float acc[UB][16];
    #pragma unroll
    for (int u = 0; u < UB; ++u)
        #pragma unroll
        for (int i = 0; i < 16; ++i) acc[u][i] = 0.f;
    for (int icb = 0; icb < C_IN; icb += ICB) {
        __syncthreads();
        for (int e = t; e < ICB * 6 * 66; e += 256) {
            int col = e % 66; int tmp = e / 66; int row = tmp % 6; int ic = tmp / 6;
            int h = uh0 - 1 + row; int ww = col - 1;
            float v = 0.f;
            if (h >= 0 && h < HW && ww >= 0 && ww < HW)
                v = x[((n * C_IN + icb + ic) * HW + h) * HW + ww];
            xs[ic][row][col] = v;
        }
        for (int e = t; e < 9 * ICB * 64; e += 256) {
            int oc = e & 63; int ic = (e >> 6) & (ICB - 1); int pq = e >> 9;
            esw[pq][ic][oc] = w[(pq * C_IN + icb + ic) * C_OUT + ocb + oc];
        }
        __syncthreads();
        float ereg[18];
        #pragma unroll
        for (int j = 0; j < 18; ++j) {
            int e = t + j * 256; int oc = e & 63; int ic = (e >> 6) & (ICB - 1);
            int tap = e >> 9; int t3 = tap / 3, s3 = tap - t3 * 3;
            int m = 2 * t3 + 1 - pu; int nn = 2 * s3 + 1 - pv;
            float gm0 = Gf(m), gm1 = Gf(m - 1), gm2 = Gf(m - 2);
            float gn0 = Gf(nn), gn1 = Gf(nn - 1), gn2 = Gf(nn - 2);
            float s =
              gm0 * (gn0 * esw[0][ic][oc] + gn1 * esw[1][ic][oc] + gn2 * esw[2][ic][oc])
            + gm1 * (gn0 * esw[3][ic][oc] + gn1 * esw[4][ic][oc] + gn2 * esw[5][ic][oc])
            + gm2 * (gn0 * esw[6][ic][oc] + gn1 * esw[7][ic][oc] + gn2 * esw[8][ic][oc]);
            ereg[j] = s * COEF;
        }
        __syncthreads();
        #pragma unroll
        for (int j = 0; j < 18; ++j) {
            int e = t + j * 256; int oc = e & 63; int ic = (e >> 6) & (ICB - 1);
            int tap = e >> 9;
            esw[tap][ic][oc] = ereg[j];
        }
        __syncthreads();
        for (int ic = 0; ic < ICB; ++ic) {
            #pragma unroll
            for (int t3 = 0; t3 < 3; ++t3) {
                #pragma unroll
                for (int s3 = 0; s3 < 3; ++s3) {
                    const int tap = t3 * 3 + s3;
                    float ev[16];
                    #pragma unroll
                    for (int r = 0; r < 4; ++r)
                        *(float4*)&ev[r * 4] = *(const float4*)&esw[tap][ic][wg * 16 + r * 4];
                    float xv[UB];
                    #pragma unroll
                    for (int u = 0; u < UB; ++u) xv[u] = xs[ic][u + t3][lane + s3];
                    #pragma unroll
                    for (int u = 0; u < UB; ++u)
                        #pragma unroll
                        for (int i = 0; i < 16; ++i) acc[u][i] += xv[u] * ev[i];
                }
            }
        }
    }
    #pragma unroll
    for (int u = 0; u < UB; ++u) {
        int urow = 2 * (uh0 + u) + pu;
        #pragma unroll
        for (int i = 0; i < 16; ++i) {
            int oc = ocb + wg * 16 + i;
            out[((n * C_OUT + oc) * 128 + urow) * 128 + 2 * lane + pv] = acc[u][i];
        }
    }
}

extern "C" void kernel_launch(void* const* d_in, const int* in_sizes, int n_in,
                              void* d_out, int out_size, void* d_ws, size_t ws_size,
                              hipStream_t stream) {
    const float* x = (const float*)d_in[0];   // (8,512,64,64) fp32
    const float* w = (const float*)d_in[1];   // (3,3,512,512) fp32 HWIO
    float* out = (float*)d_out;               // (8,512,128,128) fp32

    if (ws_size >= WS_NEED) {
        short* ews = (short*)d_ws;
        short* xtp = (short*)((char*)d_ws + E_WS_BYTES);
        prep_e_kernel<<<4608, 256, 0, stream>>>(w, ews);
        xpose_kernel<<<4224, 256, 0, stream>>>(x, xtp);
        conv_mfma_kernel<<<2048, 256, 0, stream>>>(xtp, ews, out);
    } else {
        dim3 grid(8, 128, 4);
        conv_par_kernel<<<grid, 256, 0, stream>>>(x, w, out);
    }
}

// Round 6
// 585.550 us; speedup vs baseline: 1.0022x; 1.0022x over previous
//
#include <hip/hip_runtime.h>
#include <stdint.h>

#define AS1 __attribute__((address_space(1)))
#define AS3 __attribute__((address_space(3)))

typedef short v8s  __attribute__((ext_vector_type(8)));
typedef float v4f  __attribute__((ext_vector_type(4)));
typedef float v16f __attribute__((ext_vector_type(16)));

#define C_IN  512
#define C_OUT 512
#define HW    64
#define COEF  9.20711955e-04f   // 1 / (16 * sqrt(9*512))

// E layout: [pu(2)][ocb(16)][icb(16)] chunks of [tap(18)][oc_l(32)][slot(4)][16B]
#define E_CHUNK_SHORTS 18432
#define E_WS_BYTES     (2u*16u*16u*36864u)            // 18,874,368
// x_tp: [n(8)][hp(66)][wp(66)][512 ic] bf16, zero-padded border, ic-slot swizzled
#define XT_SHORTS      ((size_t)8*66*66*512)
#define XT_BYTES       (XT_SHORTS*2)                  // 35,684,352
#define WS_NEED        ((size_t)E_WS_BYTES + XT_BYTES)

// LDS: x tile [18 rows][34 cols][64B] = 39168 B, then E tile [18][32][64B] = 36864 B
#define XTILE_BYTES 39168
#define LDS_E_OFF   39168
#define LDS_BYTES   76032

// 16B-slot swizzle: W(p) = ((p>>1)&3) ^ ((p>>3)&3) — 4-way slot diversity within
// every p-mod-8 class (macro-bank granule), uniform at dword granule too.
#define SWZ(p) ((((p) >> 1) & 3) ^ (((p) >> 3) & 3))

__device__ __forceinline__ float Gf(int i) {
    return (i < 0 || i > 3) ? 0.f : ((i == 1 || i == 2) ? 3.f : 1.f);
}
__device__ __forceinline__ short f2bf(float f) {
    uint32_t u = __float_as_uint(f);
    u += 0x7fffu + ((u >> 16) & 1u);
    return (short)(u >> 16);
}

// ---------------- precompute: x -> padded NHWC bf16 via LDS transpose ----------
__global__ __launch_bounds__(256) void xpose_kernel(const float* __restrict__ x,
                                                    short* __restrict__ xt) {
    const int b     = blockIdx.x;
    const int icb64 = b & 7;
    const int hp    = (b >> 3) % 66;
    const int n     = (b >> 3) / 66;
    const int t     = threadIdx.x;

    __shared__ short tile[64][80];   // [w][ic_local]

    const bool hvalid = (hp >= 1 && hp <= 64);
    if (hvalid) {
        #pragma unroll
        for (int r = 0; r < 4; ++r) {
            const int i  = (t >> 4) + r * 16;     // ic_local 0..63
            const int w0 = (t & 15) * 4;          // w 0..63
            const float* src = x + ((size_t)(n * C_IN + icb64 * 64 + i) * HW + (hp - 1)) * HW + w0;
            float4 v = *(const float4*)src;
            tile[w0 + 0][i] = f2bf(v.x);
            tile[w0 + 1][i] = f2bf(v.y);
            tile[w0 + 2][i] = f2bf(v.z);
            tile[w0 + 3][i] = f2bf(v.w);
        }
    }
    __syncthreads();

    for (int u = t; u < 528; u += 256) {
        const int wp = u >> 3;
        const int gs = u & 7;
        v8s o = (v8s)0;
        if (hvalid && wp >= 1 && wp <= 64) {
            const int glog = (gs & 3) ^ SWZ(wp);
            const int il   = (gs >> 2) * 32 + glog * 8;
            o = *(const v8s*)&tile[wp - 1][il];
        }
        *(v8s*)(xt + ((size_t)(n * 66 + hp) * 66 + wp) * 512
                   + icb64 * 64 + (gs >> 2) * 32 + (gs & 3) * 8) = o;
    }
}

// ---------------- precompute: E in block-LDS image layout, bf16, swizzled -------
__global__ __launch_bounds__(256) void prep_e_kernel(const float* __restrict__ w,
                                                     short* __restrict__ ews) {
    int u = blockIdx.x * 256 + threadIdx.x;   // 1,179,648 units of 16B
    int g    = u & 3;
    int oc_l = (u >> 2) & 31;
    int tq   = u >> 7;
    int tap  = tq % 18;
    int rest = tq / 18;                        // pu*256 + ocb*16 + icb
    int icb  = rest & 15;
    int ocb  = (rest >> 4) & 15;
    int pu   = rest >> 8;
    int pv   = tap & 1;
    int ts   = tap >> 1;
    int t    = ts / 3, s = ts - t * 3;
    int m    = 2 * t + 1 - pu;
    int nn   = 2 * s + 1 - pv;
    int glog = g ^ SWZ(oc_l);
    int ic0  = icb * 32 + glog * 8;
    int oc   = ocb * 32 + oc_l;

    v8s o;
    #pragma unroll
    for (int j = 0; j < 8; ++j) {
        float acc = 0.f;
        #pragma unroll
        for (int p = 0; p < 3; ++p) {
            float gm = Gf(m - p);
            if (gm != 0.f) {
                #pragma unroll
                for (int q = 0; q < 3; ++q) {
                    float gn = Gf(nn - q);
                    if (gn != 0.f)
                        acc += gm * gn * w[((size_t)(p * 3 + q) * C_IN + ic0 + j) * C_OUT + oc];
                }
            }
        }
        o[j] = f2bf(acc * COEF);
    }
    *(v8s*)(ews + (size_t)u * 8) = o;
}

// ---------------- main MFMA kernel (32x32x16) -----------------------------------
__global__ __launch_bounds__(256, 2) void conv_mfma_kernel(const short* __restrict__ xt,
                                                           const short* __restrict__ ews,
                                                           float* __restrict__ out) {
    int bid  = blockIdx.x;
    int wgid = (bid & 7) * 256 + (bid >> 3);   // bijective XCD swizzle (2048 % 8 == 0)
    int vhb = wgid & 1;  wgid >>= 1;
    int uhb = wgid & 3;  wgid >>= 2;
    int n   = wgid & 7;  wgid >>= 3;
    int ocb = wgid & 15; wgid >>= 4;
    int pu  = wgid;
    const int uh0 = uhb * 16, vh0 = vhb * 32;

    __shared__ char lds_raw[LDS_BYTES];
    AS3 char* lds3 = (AS3 char*)lds_raw;

    const int tid  = threadIdx.x;
    const int lane = tid & 63;
    const int wid  = tid >> 6;      // wave's uh-quarter (0..3)
    const int l31  = lane & 31;
    const int hi   = lane >> 5;

    // x staging: 2448 units of 16B -> (row 0..17, col 0..33, slot 0..3)
    const short* gx[10];
    bool xact[10];
    #pragma unroll
    for (int it = 0; it < 10; ++it) {
        int unit  = it * 256 + tid;
        xact[it]  = unit < 2448;
        int chunk = unit >> 2;
        int cslot = unit & 3;
        int row   = chunk / 34;
        int c     = chunk - row * 34;
        if (!xact[it]) { row = 0; c = 0; }
        gx[it] = xt + ((size_t)(n * 66 + (uh0 + row)) * 66 + (vh0 + c)) * 512 + cslot * 8;
    }
    // E staging source (36864 B per icb: 9 iters x 256 lanes x 16B)
    const short* esrc0 = ews + ((size_t)((pu * 16 + ocb) * 16)) * E_CHUNK_SHORTS + (size_t)tid * 8;

    v16f acc[4][2];   // [u][pv]
    #pragma unroll
    for (int u = 0; u < 4; ++u)
        #pragma unroll
        for (int pv = 0; pv < 2; ++pv)
            acc[u][pv] = (v16f)0.f;

    const int ocx = SWZ(l31);

    for (int icb = 0; icb < 16; ++icb) {
        __syncthreads();   // all waves done reading previous tiles
        // stage E (linear copy of pre-swizzled image)
        const short* es = esrc0 + (size_t)icb * E_CHUNK_SHORTS;
        #pragma unroll
        for (int it = 0; it < 9; ++it) {
            __builtin_amdgcn_global_load_lds((const AS1 void*)(es + it * 2048),
                (AS3 void*)(lds3 + LDS_E_OFF + (it * 256 + wid * 64) * 16), 16, 0, 0);
        }
        // stage x (pre-swizzled source, linear dest)
        #pragma unroll
        for (int it = 0; it < 10; ++it) {
            if (xact[it])
                __builtin_amdgcn_global_load_lds((const AS1 void*)(gx[it] + icb * 32),
                    (AS3 void*)(lds3 + (it * 256 + wid * 64) * 16), 16, 0, 0);
        }
        __syncthreads();   // compiler emits vmcnt(0) drain before this

        // compute: per s-shift, per 16-ic ksub: 6 A-frags (shared across 3 t), 6 B-frags
        #pragma unroll
        for (int s = 0; s < 3; ++s) {
            const int c  = l31 + s;            // tile col (vh + s)
            const int cx = SWZ(c);
            #pragma unroll
            for (int ksub = 0; ksub < 2; ++ksub) {
                const int slot = ksub * 2 + hi;            // 8-ic group within icb
                const char* xb = lds_raw + c * 64 + ((slot ^ cx) * 16);
                v8s A[6];
                #pragma unroll
                for (int rr = 0; rr < 6; ++rr)
                    A[rr] = *(const v8s*)(xb + (wid * 4 + rr) * (34 * 64));
                const int eoff = l31 * 64 + ((slot ^ ocx) * 16);
                #pragma unroll
                for (int t = 0; t < 3; ++t) {
                    #pragma unroll
                    for (int pv = 0; pv < 2; ++pv) {
                        v8s B = *(const v8s*)(lds_raw + LDS_E_OFF
                                              + ((t * 3 + s) * 2 + pv) * 2048 + eoff);
                        #pragma unroll
                        for (int u = 0; u < 4; ++u)
                            acc[u][pv] = __builtin_amdgcn_mfma_f32_32x32x16_bf16(
                                             A[u + t], B, acc[u][pv], 0, 0, 0);
                    }
                }
            }
        }
    }

    // epilogue: D col = lane&31 (oc), row = (reg&3) + 8*(reg>>2) + 4*(lane>>5) (vh)
    const int oc_g = ocb * 32 + l31;
    float* ob = out + ((size_t)(n * C_OUT + oc_g)) * 128 * 128;
    #pragma unroll
    for (int u = 0; u < 4; ++u) {
        const int h = 2 * (uh0 + wid * 4 + u) + pu;
        #pragma unroll
        for (int rg = 0; rg < 8; ++rg) {
            const int reg  = rg * 2;
            const int vh_l = (reg & 3) + 8 * (reg >> 2) + 4 * hi;
            v4f f;
            f[0] = acc[u][0][reg];
            f[1] = acc[u][1][reg];
            f[2] = acc[u][0][reg + 1];
            f[3] = acc[u][1][reg + 1];
            *(v4f*)(ob + (size_t)h * 128 + 2 * (vh0 + vh_l)) = f;
        }
    }
}

// ---------------- fallback (validated round-1 VALU kernel) ----------------------
#define ICB 8
#define UB  4
__global__ __launch_bounds__(256) void conv_par_kernel(
        const float* __restrict__ x, const float* __restrict__ w,
        float* __restrict__ out) {
    const int octile = blockIdx.x;
    const int n      = blockIdx.y >> 4;
    const int uhb    = blockIdx.y & 15;
    const int pu     = blockIdx.z >> 1;
    const int pv     = blockIdx.z & 1;
    const int t    = threadIdx.x;
    const int lane = t & 63;
    const int wg   = t >> 6;
    const int ocb  = octile * 64;
    const int uh0  = uhb * UB;
    __shared__ float xs[ICB][6][66];
    __shared__ float esw[9][ICB][64];
    float acc[UB][16];
    #pragma unroll
    for (int u = 0; u < UB; ++u)
        #pragma unroll
        for (int i = 0; i < 16; ++i) acc[u][i] = 0.f;
    for (int icb = 0; icb < C_IN; icb += ICB) {
        __syncthreads();
        for (int e = t; e < ICB * 6 * 66; e += 256) {
            int col = e % 66; int tmp = e / 66; int row = tmp % 6; int ic = tmp / 6;
            int h = uh0 - 1 + row; int ww = col - 1;
            float v = 0.f;
            if (h >= 0 && h < HW && ww >= 0 && ww < HW)
                v = x[((n * C_IN + icb + ic) * HW + h) * HW + ww];
            xs[ic][row][col] = v;
        }
        for (int e = t; e < 9 * ICB * 64; e += 256) {
            int oc = e & 63; int ic = (e >> 6) & (ICB - 1); int pq = e >> 9;
            esw[pq][ic][oc] = w[(pq * C_IN + icb + ic) * C_OUT + ocb + oc];
        }
        __syncthreads();
        float ereg[18];
        #pragma unroll
        for (int j = 0; j < 18; ++j) {
            int e = t + j * 256; int oc = e & 63; int ic = (e >> 6) & (ICB - 1);
            int tap = e >> 9; int t3 = tap / 3, s3 = tap - t3 * 3;
            int m = 2 * t3 + 1 - pu; int nn = 2 * s3 + 1 - pv;
            float gm0 = Gf(m), gm1 = Gf(m - 1), gm2 = Gf(m - 2);
            float gn0 = Gf(nn), gn1 = Gf(nn - 1), gn2 = Gf(nn - 2);
            float s =
              gm0 * (gn0 * esw[0][ic][oc] + gn1 * esw[1][ic][oc] + gn2 * esw[2][ic][oc])
            + gm1 * (gn0 * esw[3][ic][oc] + gn1 * esw[4][ic][oc] + gn2 * esw[5][ic][oc])
            + gm2 * (gn0 * esw[6][ic][oc] + gn1 * esw[7][ic][oc] + gn2 * esw[8][ic][oc]);
            ereg[j] = s * COEF;
        }
        __syncthreads();
        #pragma unroll
        for (int j = 0; j < 18; ++j) {
            int e = t + j * 256; int oc = e & 63; int ic = (e >> 6) & (ICB - 1);
            int tap = e >> 9;
            esw[tap][ic][oc] = ereg[j];
        }
        __syncthreads();
        for (int ic = 0; ic < ICB; ++ic) {
            #pragma unroll
            for (int t3 = 0; t3 < 3; ++t3) {
                #pragma unroll
                for (int s3 = 0; s3 < 3; ++s3) {
                    const int tap = t3 * 3 + s3;
                    float ev[16];
                    #pragma unroll
                    for (int r = 0; r < 4; ++r)
                        *(float4*)&ev[r * 4] = *(const float4*)&esw[tap][ic][wg * 16 + r * 4];
                    float xv[UB];
                    #pragma unroll
                    for (int u = 0; u < UB; ++u) xv[u] = xs[ic][u + t3][lane + s3];
                    #pragma unroll
                    for (int u = 0; u < UB; ++u)
                        #pragma unroll
                        for (int i = 0; i < 16; ++i) acc[u][i] += xv[u] * ev[i];
                }
            }
        }
    }
    #pragma unroll
    for (int u = 0; u < UB; ++u) {
        int urow = 2 * (uh0 + u) + pu;
        #pragma unroll
        for (int i = 0; i < 16; ++i) {
            int oc = ocb + wg * 16 + i;
            out[((n * C_OUT + oc) * 128 + urow) * 128 + 2 * lane + pv] = acc[u][i];
        }
    }
}

extern "C" void kernel_launch(void* const* d_in, const int* in_sizes, int n_in,
                              void* d_out, int out_size, void* d_ws, size_t ws_size,
                              hipStream_t stream) {
    const float* x = (const float*)d_in[0];   // (8,512,64,64) fp32
    const float* w = (const float*)d_in[1];   // (3,3,512,512) fp32 HWIO
    float* out = (float*)d_out;               // (8,512,128,128) fp32

    if (ws_size >= WS_NEED) {
        short* ews = (short*)d_ws;
        short* xtp = (short*)((char*)d_ws + E_WS_BYTES);
        prep_e_kernel<<<4608, 256, 0, stream>>>(w, ews);
        xpose_kernel<<<4224, 256, 0, stream>>>(x, xtp);
        conv_mfma_kernel<<<2048, 256, 0, stream>>>(xtp, ews, out);
    } else {
        dim3 grid(8, 128, 4);
        conv_par_kernel<<<grid, 256, 0, stream>>>(x, w, out);
    }
}